// Round 3
// baseline (63.190 us; speedup 1.0000x reference)
//
#include <hip/hip_runtime.h>

// MultiviewFeatureFusion: features (32768, 2048) f32, pids (32768,) int
//   fusion_features = features.reshape(8192, 4, 2048).sum(axis=1)  -> (8192, 2048) f32
//   fusion_pids     = pids[::4].astype(float32)                    -> (8192,)      f32
// d_out = [fusion_features flat | fusion_pids], 8192*2048 + 8192 floats.

#define VIEW_NUM 4
#define N_ROWS   32768
#define CDIM     2048
#define CHUNK    (N_ROWS / VIEW_NUM)   // 8192
#define C4       (CDIM / 4)            // 512 float4 per output row
#define BLOCK    256
#define GRID     4096
#define ITERS    4                     // GRID*BLOCK*ITERS == CHUNK*C4

// Native clang vector type: __builtin_nontemporal_* requires scalar/native-vector,
// not HIP_vector_type structs.
typedef float f32x4 __attribute__((ext_vector_type(4)));

__global__ __launch_bounds__(BLOCK)
void MultiviewFeatureFusion_kernel(const f32x4* __restrict__ feat,
                                   const int*   __restrict__ pids,
                                   f32x4*       __restrict__ out_feat,
                                   float*       __restrict__ out_pids) {
    const int tid      = blockIdx.x * BLOCK + threadIdx.x;
    const int nthreads = GRID * BLOCK;           // 1,048,576

    // Independent, fully-coalesced iterations: wave-contiguous addresses within
    // each iteration; iterations 16 MiB apart. Unrolled so the compiler keeps
    // all 16 loads in flight and pipelines stores against next-iter loads.
    #pragma unroll
    for (int it = 0; it < ITERS; ++it) {
        const int v    = tid + it * nthreads;    // output float4 index
        const int row  = v >> 9;                 // v / C4
        const int col4 = v & (C4 - 1);           // v % C4

        const f32x4* p = feat + (size_t)row * (VIEW_NUM * C4) + col4;
        f32x4 a = __builtin_nontemporal_load(p);
        f32x4 b = __builtin_nontemporal_load(p + C4);
        f32x4 c = __builtin_nontemporal_load(p + 2 * C4);
        f32x4 d = __builtin_nontemporal_load(p + 3 * C4);

        f32x4 s = (a + b) + (c + d);
        __builtin_nontemporal_store(s, out_feat + v);
    }

    if (tid < CHUNK) {
        out_pids[tid] = (float)pids[tid * VIEW_NUM];
    }
}

extern "C" void kernel_launch(void* const* d_in, const int* in_sizes, int n_in,
                              void* d_out, int out_size, void* d_ws, size_t ws_size,
                              hipStream_t stream) {
    const f32x4* feat = (const f32x4*)d_in[0];
    const int*   pids = (const int*)d_in[1];

    f32x4* out_feat = (f32x4*)d_out;
    float* out_pids = (float*)d_out + (size_t)CHUNK * CDIM;

    MultiviewFeatureFusion_kernel<<<GRID, BLOCK, 0, stream>>>(feat, pids, out_feat, out_pids);
}

// Round 4
// 56.866 us; speedup vs baseline: 1.1112x; 1.1112x over previous
//
#include <hip/hip_runtime.h>

// MultiviewFeatureFusion: features (32768, 2048) f32, pids (32768,) int
//   fusion_features = features.reshape(8192, 4, 2048).sum(axis=1)  -> (8192, 2048) f32
//   fusion_pids     = pids[::4].astype(float32)                    -> (8192,)      f32
// d_out = [fusion_features flat | fusion_pids], 8192*2048 + 8192 floats.
//
// Policy: loads CACHEABLE (input may be partially L3-resident across graph
// replays; 256 MiB == L3 size), stores NONTEMPORAL (64 MiB output stream must
// not evict input lines from L2/L3).

#define VIEW_NUM 4
#define N_ROWS   32768
#define CDIM     2048
#define CHUNK    (N_ROWS / VIEW_NUM)   // 8192
#define C4       (CDIM / 4)            // 512 float4 per output row
#define BLOCK    512
#define GRID     2048
#define ITERS    4                     // GRID*BLOCK*ITERS == CHUNK*C4 == 4,194,304

typedef float f32x4 __attribute__((ext_vector_type(4)));

__global__ __launch_bounds__(BLOCK)
void MultiviewFeatureFusion_kernel(const f32x4* __restrict__ feat,
                                   const int*   __restrict__ pids,
                                   f32x4*       __restrict__ out_feat,
                                   float*       __restrict__ out_pids) {
    const int tid      = blockIdx.x * BLOCK + threadIdx.x;
    const int nthreads = GRID * BLOCK;           // 1,048,576

    #pragma unroll
    for (int it = 0; it < ITERS; ++it) {
        const int v    = tid + it * nthreads;    // output float4 index
        const int row  = v >> 9;                 // v / C4
        const int col4 = v & (C4 - 1);           // v % C4

        const f32x4* p = feat + (size_t)row * (VIEW_NUM * C4) + col4;
        f32x4 a = p[0];          // cacheable reads
        f32x4 b = p[C4];
        f32x4 c = p[2 * C4];
        f32x4 d = p[3 * C4];

        f32x4 s = (a + b) + (c + d);
        __builtin_nontemporal_store(s, out_feat + v);   // streaming write
    }

    if (tid < CHUNK) {
        out_pids[tid] = (float)pids[tid * VIEW_NUM];
    }
}

extern "C" void kernel_launch(void* const* d_in, const int* in_sizes, int n_in,
                              void* d_out, int out_size, void* d_ws, size_t ws_size,
                              hipStream_t stream) {
    const f32x4* feat = (const f32x4*)d_in[0];
    const int*   pids = (const int*)d_in[1];

    f32x4* out_feat = (f32x4*)d_out;
    float* out_pids = (float*)d_out + (size_t)CHUNK * CDIM;

    MultiviewFeatureFusion_kernel<<<GRID, BLOCK, 0, stream>>>(feat, pids, out_feat, out_pids);
}